// Round 4
// baseline (242.335 us; speedup 1.0000x reference)
//
#include <hip/hip_runtime.h>
#include <hip/hip_bf16.h>
#include <hip/hip_cooperative_groups.h>

typedef unsigned short u16;
typedef __attribute__((ext_vector_type(8))) short s16x8;
typedef __attribute__((ext_vector_type(4))) float f32x4;
typedef __attribute__((address_space(3))) u16 lds_u16;
typedef __attribute__((address_space(1))) const u16 g_u16;

#define CIN 256
#define COUT 256
#define NPIX 3136      // 56*56
#define CWROW 168      // 336B stride, gcd(336,128)=16: 2-way (free) LDS access on A-frag reads
#define CWPB (16 * COUT * CWROW)   // 688128 elems per batch
// xq layout: [b][ck(16)][h'(58)][w'(58)][ci(16)] bf16, halo rows/cols zero. row = 928 elems.
// cw layout: [b][ck(16)][o(256)][t(10)+pad][ci(16)] bf16, t=9 zero pad, elems 160..167 dead pad.
// parts layout: [hg(7)][b(16)][c(256)] f32 raw GAP partial sums (no atomics, no memset needed).

__device__ __forceinline__ u16 f2b(float f) {   // f32 -> bf16 bits, RNE
  union { float f; unsigned u; } c; c.f = f;
  unsigned r = (c.u + 0x7FFFu + ((c.u >> 16) & 1u)) >> 16;
  return (u16)r;
}

// ---------------- phase 1 unit: transpose 8 rows + GAP partial (proven r2 body; partials store) --
__device__ __forceinline__ void transpose_unit(int hg, int ck, int b,
    const float* __restrict__ x, u16* __restrict__ xq, float* __restrict__ parts,
    u16* tile /*7424 u16 = 14,848 B*/, int tid) {
  const int ci = tid >> 4, sub = tid & 15;
  if (tid < 32) {                 // zero w'-halo units (w' = 0, 57 -> c in {0,1,114,115})
    int r = tid >> 2, c4 = tid & 3;
    int u = r * 116 + (c4 < 2 ? c4 : 112 + c4);
    int us = u ^ ((u >> 3) & 7);
    *(uint4*)&tile[us * 8] = (uint4){0, 0, 0, 0};
  }
  const float* src = x + ((size_t)(b * CIN + ck * 16 + ci) * NPIX + (size_t)hg * 448);
  float s = 0.f;
#pragma unroll
  for (int it = 0; it < 7; ++it) {
    int p = it * 16 + sub;                      // [0,112): 8 rows x 14 float4
    int row = p / 14, wq = p - row * 14;
    float4 v = *(const float4*)(src + p * 4);
    s += v.x + v.y + v.z + v.w;
    u16 q[4] = { f2b(v.x), f2b(v.y), f2b(v.z), f2b(v.w) };
#pragma unroll
    for (int k = 0; k < 4; ++k) {
      int wp = wq * 4 + 1 + k;                  // w' in [1,56]
      int u = (row * 58 + wp) * 2 + (ci >> 3);
      int us = u ^ ((u >> 3) & 7);
      tile[us * 8 + (ci & 7)] = q[k];
    }
  }
  for (int off = 8; off; off >>= 1) s += __shfl_down(s, off, 16);  // 16 lanes share ci
  if (sub == 0) parts[(hg * 16 + b) * 256 + ck * 16 + ci] = s;     // plain store (no atomic)
  __syncthreads();
  uint4* dst = (uint4*)(xq + ((size_t)(b * 16 + ck) * 58 + hg * 8 + 1) * 928);
  for (int idx = tid; idx < 928; idx += 256) {  // 8 rows x 116 uint4, contiguous
    int us = idx ^ ((idx >> 3) & 7);
    dst[idx] = *(const uint4*)&tile[us * 8];
  }
  if (hg == 0 && tid < 116)                     // halo row h'=0
    ((uint4*)(xq + ((size_t)(b * 16 + ck) * 58) * 928))[tid] = (uint4){0, 0, 0, 0};
  if (hg == 6 && tid < 116)                     // halo row h'=57
    ((uint4*)(xq + ((size_t)(b * 16 + ck) * 58 + 57) * 928))[tid] = (uint4){0, 0, 0, 0};
  __syncthreads();                              // tile reuse guard (fused calls 4 units serially)
}

// ---------------- phase 2 unit: combine (routing fused; parts pre-reduced in LDS) ----------------
__device__ __forceinline__ void combine_unit(int o, const float* __restrict__ W,
    const float* __restrict__ parts, const float* __restrict__ rw,
    const float* __restrict__ rb, u16* __restrict__ cw, char* smem, int tid) {
  float* pooled_lds = (float*)smem;                 // [16][256] f32 = 16,384 B
  float* rs = (float*)(smem + 16384);               // [128] f32
  u16* st = (u16*)(smem + 16896);                   // [2][16*CWROW] = 10,752 B
  for (int b = 0; b < 16; ++b) {                    // pre-reduce 7 hg-partials
    float s = 0.f;
#pragma unroll
    for (int hg = 0; hg < 7; ++hg) s += parts[(hg * 16 + b) * 256 + tid];
    pooled_lds[b * 256 + tid] = s;
  }
  for (int i = tid; i < (2 * 16 * CWROW) / 8; i += 256)   // zero staging (covers t=9 + pad)
    ((uint4*)st)[i] = (uint4){0, 0, 0, 0};
  __syncthreads();
  if (tid < 128) {                       // routing: r[b][e]
    int b = tid >> 3, e = tid & 7;
    float s = rb[e];
    const float* pb = pooled_lds + b * 256;
    const float* we = rw + e * CIN;
    for (int c = 0; c < CIN; ++c) s += (pb[c] * (1.f / 3136.f)) * we[c];
    rs[tid] = 1.f / (1.f + __expf(-s));
  }
  float wreg[8][9];
#pragma unroll
  for (int e = 0; e < 8; ++e) {
    const float* wp = W + ((size_t)(e * COUT + o)) * 2304 + tid;
#pragma unroll
    for (int k = 0; k < 9; ++k) wreg[e][k] = wp[k * 256];
  }
  int slot[9];
#pragma unroll
  for (int k = 0; k < 9; ++k) {
    int j = tid + k * 256, ci = j / 9, t = j - ci * 9;
    slot[k] = (ci >> 4) * CWROW + t * 16 + (ci & 15);
  }
  __syncthreads();
  for (int b = 0; b < 16; ++b) {
    u16* sb = st + (b & 1) * (16 * CWROW);
    float rv[8];
#pragma unroll
    for (int e = 0; e < 8; ++e) rv[e] = rs[b * 8 + e];
#pragma unroll
    for (int k = 0; k < 9; ++k) {
      float a = 0.f;
#pragma unroll
      for (int e = 0; e < 8; ++e) a += rv[e] * wreg[e][k];
      sb[slot[k]] = f2b(a);
    }
    __syncthreads();
    u16* dstb = cw + (size_t)b * CWPB;
    for (int i = tid; i < 336; i += 256) {   // 16 ck x 21 uint4, each run 336B contiguous
      int ck = i / 21, q = i - ck * 21;
      *(uint4*)(dstb + ck * (256 * CWROW) + o * CWROW + q * 8) =
          *(const uint4*)(sb + ck * CWROW + q * 8);
    }
  }
}

// ---------------- phase 3 unit: conv (double-buffered + XCD-local; xs tightened to 18,560B) -----
__device__ __forceinline__ void conv_unit(int l, const u16* __restrict__ xq,
    const u16* __restrict__ cw, const float* __restrict__ bng, const float* __restrict__ bnb,
    const float* __restrict__ bnm, const float* __restrict__ bnv, float* __restrict__ out,
    char* smem, int tid) {
  const int xcd = l & 7, s = l >> 3;          // s in 0..55
  const int bb = (s >= 28) ? 1 : 0;
  const int b = xcd + 8 * bb;
  const int r = s - 28 * bb;                  // 0..27 = 4 o-blocks x 7 h-blocks
  const int ob = r / 7;
  const int o0 = ob * 64, h0 = (r - ob * 7) * 8;
  const int wv = tid >> 6, lane = tid & 63, quad = lane >> 4, ln = lane & 15;

  u16* xsb[2] = { (u16*)smem,            (u16*)(smem + 18560) };  // 2 x 9,280 u16 (10x928)
  u16* asb[2] = { (u16*)(smem + 37120),  (u16*)(smem + 58624) };  // 2 x 10,752 u16 -> 80,128 B

  f32x4 acc[4][7];
#pragma unroll
  for (int ms = 0; ms < 4; ++ms)
#pragma unroll
    for (int ns = 0; ns < 7; ++ns) acc[ms][ns] = (f32x4){0.f, 0.f, 0.f, 0.f};

  int bsite[7];
#pragma unroll
  for (int ns = 0; ns < 7; ++ns) {
    int pi = ns * 16 + ln;
    int hr = (pi >= 56) ? 1 : 0;
    int wc = pi - hr * 56;
    bsite[ns] = ((2 * wv + hr) * 58 + wc) * 16;
  }

  auto STAGE = [&](int ck, int buf) {
    const u16* xsrc = xq + ((size_t)(b * 16 + ck) * 58 + h0) * 928;      // 10 rows contiguous
    const u16* asrc = cw + (size_t)b * CWPB + ((size_t)ck * COUT + o0) * CWROW; // 64 o's contig
    for (int g = wv; g < 40; g += 4) {
      if (g < 18)
        __builtin_amdgcn_global_load_lds((g_u16*)(xsrc + g * 512 + lane * 8),
                                         (lds_u16*)(xsb[buf] + g * 512), 16, 0, 0);
      else if (g == 18) {                      // 128-B tail: exec-masked partial group
        if (lane < 8)
          __builtin_amdgcn_global_load_lds((g_u16*)(xsrc + 9216 + lane * 8),
                                           (lds_u16*)(xsb[buf] + 9216), 16, 0, 0);
      } else
        __builtin_amdgcn_global_load_lds((g_u16*)(asrc + (g - 19) * 512 + lane * 8),
                                         (lds_u16*)(asb[buf] + (g - 19) * 512), 16, 0, 0);
    }
  };

  auto COMPUTE = [&](int buf) {
#pragma unroll
    for (int tp = 0; tp < 5; ++tp) {
      int t = tp * 2 + (quad >> 1);
      int dy, dx;
      if (t < 9) { dy = t / 3; dx = t - dy * 3; } else { dy = 1; dx = 1; }  // t=9: zero weights
      const int boff = (dy * 58 + dx) * 16 + (quad & 1) * 8;
      s16x8 af[4];
#pragma unroll
      for (int ms = 0; ms < 4; ++ms)
        af[ms] = *(const s16x8*)&asb[buf][(ms * 16 + ln) * CWROW + tp * 32 + quad * 8];
#pragma unroll
      for (int ns = 0; ns < 7; ++ns) {
        s16x8 bfr = *(const s16x8*)&xsb[buf][bsite[ns] + boff];
#pragma unroll
        for (int ms = 0; ms < 4; ++ms)
          acc[ms][ns] = __builtin_amdgcn_mfma_f32_16x16x32_bf16(af[ms], bfr, acc[ms][ns], 0, 0, 0);
      }
    }
  };

  STAGE(0, 0);
  __syncthreads();
  for (int ck = 0; ck < 16; ck += 2) {
    STAGE(ck + 1, 1);
    COMPUTE(0);
    __syncthreads();
    if (ck < 14) STAGE(ck + 2, 0);
    COMPUTE(1);
    __syncthreads();
  }

  // ---- epilogue: BN + SiLU, f32 store ----
#pragma unroll
  for (int ms = 0; ms < 4; ++ms) {
#pragma unroll
    for (int rr = 0; rr < 4; ++rr) {
      int o = o0 + ms * 16 + quad * 4 + rr;     // C/D: row = quad*4 + reg
      float inv = bng[o] * rsqrtf(bnv[o] + 1e-5f);
      float bias = bnb[o] - bnm[o] * inv;
      float* obp = out + ((size_t)(b * COUT + o)) * NPIX;
#pragma unroll
      for (int ns = 0; ns < 7; ++ns) {
        int pi = ns * 16 + ln;                  // C/D: col = lane&15
        int hr = (pi >= 56) ? 1 : 0;
        int wc = pi - hr * 56;
        int hg = h0 + 2 * wv + hr;
        float v = acc[ms][ns][rr] * inv + bias;
        v = v / (1.f + __expf(-v));             // SiLU
        obp[hg * 56 + wc] = v;
      }
    }
  }
}

// ---------------- standalone kernels (fallback path: 3 nodes, no memset) ----------------
__global__ __launch_bounds__(256)
void transpose_gap_kernel(const float* __restrict__ x, u16* __restrict__ xq,
                          float* __restrict__ parts) {
  __shared__ __align__(16) u16 tile[7424];
  transpose_unit(blockIdx.x, blockIdx.y, blockIdx.z, x, xq, parts, tile, threadIdx.x);
}

__global__ __launch_bounds__(256)
void combine_kernel(const float* __restrict__ W, const float* __restrict__ parts,
                    const float* __restrict__ rw, const float* __restrict__ rb,
                    u16* __restrict__ cw) {
  __shared__ __align__(16) char smem[27648];
  combine_unit(blockIdx.x, W, parts, rw, rb, cw, smem, threadIdx.x);
}

__global__ __launch_bounds__(256)
void conv_kernel(const u16* __restrict__ xq, const u16* __restrict__ cw,
                 const float* __restrict__ bng, const float* __restrict__ bnb,
                 const float* __restrict__ bnm, const float* __restrict__ bnv,
                 float* __restrict__ out) {
  __shared__ __align__(16) char smem[80128];
  conv_unit(blockIdx.x, xq, cw, bng, bnb, bnm, bnv, out, smem, threadIdx.x);
}

// ---------------- fused cooperative kernel: 1 node instead of 4 ----------------
// grid 448 x 256. Phase 1: each block does 4 transpose units, batch matched to conv's
// XCD mapping (b = (l&7) + 8*parity) so xq stays XCD-local. Phase 2: blocks 0..255 combine.
// Phase 3: conv. grid.sync() + threadfence between phases (device-scope visibility).
__global__ __launch_bounds__(256)
void fused_kernel(const float* __restrict__ x, const float* __restrict__ rw,
                  const float* __restrict__ rb, const float* __restrict__ W,
                  const float* __restrict__ bng, const float* __restrict__ bnb,
                  const float* __restrict__ bnm, const float* __restrict__ bnv,
                  float* __restrict__ out, u16* __restrict__ cw, u16* __restrict__ xq,
                  float* __restrict__ parts) {
  __shared__ __align__(16) char smem[80128];
  const int l = blockIdx.x, tid = threadIdx.x;
  {
    const int xcd = l & 7, s = l >> 3;
    const int b = xcd + 8 * (s & 1);
    const int base = (s >> 1) * 4;              // (s>>1) in 0..27 -> 4 units = 112 (hg,ck) pairs
#pragma unroll
    for (int i = 0; i < 4; ++i) {
      int idx = base + i;                       // 0..111
      int hg = idx % 7, ck = idx / 7;
      transpose_unit(hg, ck, b, x, xq, parts, (u16*)smem, tid);
    }
  }
  __threadfence();
  cooperative_groups::this_grid().sync();
  if (l < 256) combine_unit(l, W, parts, rw, rb, cw, smem, tid);
  __threadfence();
  cooperative_groups::this_grid().sync();
  conv_unit(l, xq, cw, bng, bnb, bnm, bnv, out, smem, tid);
}

extern "C" void kernel_launch(void* const* d_in, const int* in_sizes, int n_in,
                              void* d_out, int out_size, void* d_ws, size_t ws_size,
                              hipStream_t stream) {
  const float* x   = (const float*)d_in[0];
  const float* rw  = (const float*)d_in[1];
  const float* rb  = (const float*)d_in[2];
  const float* W   = (const float*)d_in[3];
  const float* bng = (const float*)d_in[4];
  const float* bnb = (const float*)d_in[5];
  const float* bnm = (const float*)d_in[6];
  const float* bnv = (const float*)d_in[7];
  float* out = (float*)d_out;

  char* wsb = (char*)d_ws;
  // cw: 16*16*256*168*2 = 22,020,096 B ; xq: 16*16*58*58*16*2 (+1 KiB pad) = 27,558,912 B
  // parts: 7*16*256*4 = 114,688 B   (total 49,693,696 B)
  u16*  cw    = (u16*)wsb;
  u16*  xq    = (u16*)(wsb + 22020096);
  float* parts = (float*)(wsb + 22020096 + 27558912);

  static int coopBlocks = -1;     // cached occupancy query (host-only, capture-safe)
  if (coopBlocks < 0) {
    int mb = 0;
    hipError_t e = hipOccupancyMaxActiveBlocksPerMultiprocessor(&mb, (const void*)fused_kernel,
                                                                256, 0);
    coopBlocks = (e == hipSuccess) ? mb : 0;
  }
  hipError_t le = hipErrorUnknown;
  if (coopBlocks >= 2) {          // need 448 co-resident blocks (2/CU on 256 CUs)
    void* args[12] = { (void*)&x, (void*)&rw, (void*)&rb, (void*)&W, (void*)&bng, (void*)&bnb,
                       (void*)&bnm, (void*)&bnv, (void*)&out, (void*)&cw, (void*)&xq,
                       (void*)&parts };
    le = hipLaunchCooperativeKernel((const void*)fused_kernel, dim3(448), dim3(256),
                                    args, 0u, stream);
  }
  if (le != hipSuccess) {         // fallback: proven 3-kernel pipeline (no memset needed now)
    transpose_gap_kernel<<<dim3(7, 16, 16), 256, 0, stream>>>(x, xq, parts);
    combine_kernel<<<256, 256, 0, stream>>>(W, parts, rw, rb, cw);
    conv_kernel<<<dim3(448), 256, 0, stream>>>(xq, cw, bng, bnb, bnm, bnv, out);
  }
}

// Round 6
// 227.009 us; speedup vs baseline: 1.0675x; 1.0675x over previous
//
#include <hip/hip_runtime.h>
#include <hip/hip_bf16.h>

typedef unsigned short u16;
typedef __attribute__((ext_vector_type(8))) short s16x8;
typedef __attribute__((ext_vector_type(4))) float f32x4;
typedef __attribute__((address_space(3))) u16 lds_u16;
typedef __attribute__((address_space(1))) const u16 g_u16;

#define CIN 256
#define COUT 256
#define NPIX 3136      // 56*56
#define CWROW 168      // 336B stride, gcd(336,128)=16 -> 2-way (free) on A-frag ds_read_b128
#define CWPB (16 * COUT * CWROW)   // 688128 elems per batch
// xq layout: [b][ck(16)][h'(58)][w'(58)][ci(16)] bf16, halo rows/cols zero. row = 928 elems.
// cw layout: [b][ck(16)][o(256)][t(10)+pad][ci(16)] bf16, t=9 zero pad, elems 160..167 dead pad.
// parts layout: [hg(7)][b(16)][c(256)] f32 raw GAP partial sums (no atomics, no memset).

__device__ __forceinline__ u16 f2b(float f) {   // f32 -> bf16 bits, RNE
  union { float f; unsigned u; } c; c.f = f;
  unsigned r = (c.u + 0x7FFFu + ((c.u >> 16) & 1u)) >> 16;
  return (u16)r;
}

// ---------------- K0: transpose x -> xq + fused GAP — r4 VERBATIM (proven) ----------------
__global__ __launch_bounds__(256)
void transpose_gap_kernel(const float* __restrict__ x, u16* __restrict__ xq,
                          float* __restrict__ parts) {
  const int hg = blockIdx.x, ck = blockIdx.y, b = blockIdx.z;
  const int tid = threadIdx.x;
  const int ci = tid >> 4, sub = tid & 15;
  __shared__ __align__(16) u16 tile[928 * 8];   // 14,848 B

  if (tid < 32) {                 // zero w'-halo units (w' = 0, 57 -> c in {0,1,114,115})
    int r = tid >> 2, c4 = tid & 3;
    int u = r * 116 + (c4 < 2 ? c4 : 112 + c4);
    int us = u ^ ((u >> 3) & 7);
    *(uint4*)&tile[us * 8] = (uint4){0, 0, 0, 0};
  }
  const float* src = x + ((size_t)(b * CIN + ck * 16 + ci) * NPIX + (size_t)hg * 448);
  float s = 0.f;
#pragma unroll
  for (int it = 0; it < 7; ++it) {
    int p = it * 16 + sub;                      // [0,112): 8 rows x 14 float4
    int row = p / 14, wq = p - row * 14;
    float4 v = *(const float4*)(src + p * 4);
    s += v.x + v.y + v.z + v.w;
    u16 q[4] = { f2b(v.x), f2b(v.y), f2b(v.z), f2b(v.w) };
#pragma unroll
    for (int k = 0; k < 4; ++k) {
      int wp = wq * 4 + 1 + k;                  // w' in [1,56]
      int u = (row * 58 + wp) * 2 + (ci >> 3);
      int us = u ^ ((u >> 3) & 7);
      tile[us * 8 + (ci & 7)] = q[k];
    }
  }
  for (int off = 8; off; off >>= 1) s += __shfl_down(s, off, 16);  // 16 lanes share ci
  if (sub == 0) parts[(hg * 16 + b) * 256 + ck * 16 + ci] = s;     // plain store
  __syncthreads();
  uint4* dst = (uint4*)(xq + ((size_t)(b * 16 + ck) * 58 + hg * 8 + 1) * 928);
  for (int idx = tid; idx < 928; idx += 256) {  // 8 rows x 116 uint4, contiguous
    int us = idx ^ ((idx >> 3) & 7);
    dst[idx] = *(const uint4*)&tile[us * 8];
  }
  if (hg == 0 && tid < 116)                     // halo row h'=0
    ((uint4*)(xq + ((size_t)(b * 16 + ck) * 58) * 928))[tid] = (uint4){0, 0, 0, 0};
  if (hg == 6 && tid < 116)                     // halo row h'=57
    ((uint4*)(xq + ((size_t)(b * 16 + ck) * 58 + 57) * 928))[tid] = (uint4){0, 0, 0, 0};
}

// ---------------- K3: combine — r4 VERBATIM (parts pre-reduce, LDS-staged stores) ----------------
__global__ __launch_bounds__(256)
void combine_kernel(const float* __restrict__ W, const float* __restrict__ parts,
                    const float* __restrict__ rw, const float* __restrict__ rb,
                    u16* __restrict__ cw) {
  const int o = blockIdx.x, tid = threadIdx.x;
  __shared__ float pooled_lds[16 * 256];            // 16,384 B
  __shared__ float rs[128];
  __shared__ __align__(16) u16 st[2][16 * CWROW];   // 10,752 B
  for (int b = 0; b < 16; ++b) {                    // pre-reduce 7 hg-partials
    float s = 0.f;
#pragma unroll
    for (int hg = 0; hg < 7; ++hg) s += parts[(hg * 16 + b) * 256 + tid];
    pooled_lds[b * 256 + tid] = s;
  }
  for (int i = tid; i < (2 * 16 * CWROW) / 8; i += 256)   // zero staging (t=9 + pad)
    ((uint4*)st)[i] = (uint4){0, 0, 0, 0};
  __syncthreads();
  if (tid < 128) {                       // routing: r[b][e]
    int b = tid >> 3, e = tid & 7;
    float s = rb[e];
    const float* pb = pooled_lds + b * 256;
    const float* we = rw + e * CIN;
    for (int c = 0; c < CIN; ++c) s += (pb[c] * (1.f / 3136.f)) * we[c];
    rs[tid] = 1.f / (1.f + __expf(-s));
  }
  float wreg[8][9];
#pragma unroll
  for (int e = 0; e < 8; ++e) {
    const float* wp = W + ((size_t)(e * COUT + o)) * 2304 + tid;
#pragma unroll
    for (int k = 0; k < 9; ++k) wreg[e][k] = wp[k * 256];
  }
  int slot[9];
#pragma unroll
  for (int k = 0; k < 9; ++k) {
    int j = tid + k * 256, ci = j / 9, t = j - ci * 9;
    slot[k] = (ci >> 4) * CWROW + t * 16 + (ci & 15);
  }
  __syncthreads();
  for (int b = 0; b < 16; ++b) {
    u16* sb = st[b & 1];
    float rv[8];
#pragma unroll
    for (int e = 0; e < 8; ++e) rv[e] = rs[b * 8 + e];
#pragma unroll
    for (int k = 0; k < 9; ++k) {
      float a = 0.f;
#pragma unroll
      for (int e = 0; e < 8; ++e) a += rv[e] * wreg[e][k];
      sb[slot[k]] = f2b(a);
    }
    __syncthreads();
    u16* dstb = cw + (size_t)b * CWPB;
    for (int i = tid; i < 336; i += 256) {   // 16 ck x 21 uint4, each run 336B contiguous
      int ck = i / 21, q = i - ck * 21;
      *(uint4*)(dstb + ck * (256 * CWROW) + o * CWROW + q * 8) =
          *(const uint4*)(sb + ck * CWROW + q * 8);
    }
  }
}

// ---------------- K4: conv v3 — depth-2 pipeline, 3 LDS buffers, counted vmcnt ----------------
// 448 threads (7 waves), grid 256 = 1 block/CU. Tile: 64 o x 14 out-rows (16 xq rows staged).
// Per ck: wave issues 7 (wave0: 8) global_load_lds; stage(ck+1) stays IN FLIGHT across the
// barrier (s_waitcnt vmcnt(7|8), never 0 until the last window) — the T4 mechanism the old
// 2-buffer schedule could not express. XCD map: xcd owns batches {2x,2x+1} (L2/L3-local).
// Rotation safety: window ck's STAGE(ck+2) overwrites buf (ck+2)%3 = COMPUTE(ck-1)'s buffer;
// the s_barrier at window start orders all waves' MFMAs (lgkmcnt-complete) before the writes.
__global__ __launch_bounds__(448, 1)
void conv_kernel(const u16* __restrict__ xq, const u16* __restrict__ cw,
                 const float* __restrict__ bng, const float* __restrict__ bnb,
                 const float* __restrict__ bnm, const float* __restrict__ bnv,
                 float* __restrict__ out) {
  const int l = blockIdx.x;
  const int xcd = l & 7, s = l >> 3;          // 32 blocks per XCD
  const int b = 2 * xcd + (s >> 4);
  const int rem = s & 15;
  const int ob = rem >> 2, hb = rem & 3;
  const int o0 = ob * 64, h0 = hb * 14;       // 4x14 = 56 rows, exact
  const int tid = threadIdx.x;
  const int wv = tid >> 6, lane = tid & 63, quad = lane >> 4, ln = lane & 15;

  __shared__ __align__(16) u16 xs[3][14848];  // 3 x 29,696 B (16 rows x 928, exact)
  __shared__ __align__(16) u16 as_[3][10752]; // 3 x 21,504 B -> total 153,600 B (1 blk/CU)

  f32x4 acc[4][7];
#pragma unroll
  for (int ms = 0; ms < 4; ++ms)
#pragma unroll
    for (int ns = 0; ns < 7; ++ns) acc[ms][ns] = (f32x4){0.f, 0.f, 0.f, 0.f};

  int bsite[7];
#pragma unroll
  for (int ns = 0; ns < 7; ++ns) {            // wave wv owns out-rows 2wv, 2wv+1 (of 14)
    int pi = ns * 16 + ln;
    int hr = (pi >= 56) ? 1 : 0;
    int wc = pi - hr * 56;
    bsite[ns] = ((2 * wv + hr) * 58 + wc) * 16;
  }
  int boffp[5];                               // ck-invariant tap offsets (hoisted)
#pragma unroll
  for (int tp = 0; tp < 5; ++tp) {
    int t = tp * 2 + (quad >> 1);
    int dy, dx;
    if (t < 9) { dy = t / 3; dx = t - dy * 3; } else { dy = 1; dx = 1; }  // t=9: zero weights
    boffp[tp] = (dy * 58 + dx) * 16 + (quad & 1) * 8;
  }
  int abase[4];
#pragma unroll
  for (int ms = 0; ms < 4; ++ms) abase[ms] = (ms * 16 + ln) * CWROW + quad * 8;

  // group map: xs = groups 0..28 (29 1KB-groups), as = groups 29..49 (21). wave0: 8, rest: 7.
  const int g0 = (wv == 0) ? 0 : 8 + (wv - 1) * 7;

  auto STAGE = [&](int ck, int buf) {
    const u16* xsrc = xq + ((size_t)(b * 16 + ck) * 58 + h0) * 928;      // 16 rows, exact
    const u16* asrc = cw + (size_t)b * CWPB + ((size_t)ck * COUT + o0) * CWROW; // 64 o contig
#pragma unroll
    for (int i = 0; i < 8; ++i) {
      if (i < 7 || wv == 0) {
        int G = g0 + i;
        if (G < 29)
          __builtin_amdgcn_global_load_lds((g_u16*)(xsrc + G * 512 + lane * 8),
                                           (lds_u16*)(&xs[buf][G * 512]), 16, 0, 0);
        else
          __builtin_amdgcn_global_load_lds((g_u16*)(asrc + (G - 29) * 512 + lane * 8),
                                           (lds_u16*)(&as_[buf][(G - 29) * 512]), 16, 0, 0);
      }
    }
  };

  auto COMPUTE = [&](int buf) {
#pragma unroll
    for (int tp = 0; tp < 5; ++tp) {
      s16x8 af[4];
#pragma unroll
      for (int ms = 0; ms < 4; ++ms)
        af[ms] = *(const s16x8*)&as_[buf][abase[ms] + tp * 32];
#pragma unroll
      for (int ns = 0; ns < 7; ++ns) {
        s16x8 bfr = *(const s16x8*)&xs[buf][bsite[ns] + boffp[tp]];
#pragma unroll
        for (int ms = 0; ms < 4; ++ms)
          acc[ms][ns] = __builtin_amdgcn_mfma_f32_16x16x32_bf16(af[ms], bfr, acc[ms][ns], 0, 0, 0);
      }
    }
  };

  STAGE(0, 0);
  STAGE(1, 1);
  // Window: counted drain (stage ck done, stage ck+1 still flying), barrier, issue ck+2, compute.
#define CONV_WINDOW(CK, BUF, SBUF, DO_STAGE, LAST)                                  \
  {                                                                                 \
    if (LAST)            asm volatile("s_waitcnt vmcnt(0)" ::: "memory");           \
    else if (wv == 0)    asm volatile("s_waitcnt vmcnt(8)" ::: "memory");           \
    else                 asm volatile("s_waitcnt vmcnt(7)" ::: "memory");           \
    __builtin_amdgcn_sched_barrier(0);                                              \
    __builtin_amdgcn_s_barrier();                                                   \
    __builtin_amdgcn_sched_barrier(0);                                              \
    if (DO_STAGE) STAGE((CK) + 2, SBUF);                                            \
    __builtin_amdgcn_s_setprio(1);                                                  \
    COMPUTE(BUF);                                                                   \
    __builtin_amdgcn_s_setprio(0);                                                  \
  }
  for (int jj = 0; jj < 5; ++jj) {            // windows ck=0..14 (buf indices static per slot)
    int ck = jj * 3;
    CONV_WINDOW(ck,     0, 2, true,      false);
    CONV_WINDOW(ck + 1, 1, 0, true,      false);
    CONV_WINDOW(ck + 2, 2, 1, (jj < 4),  false);
  }
  CONV_WINDOW(15, 0, 0, false, true);         // final window: full drain
#undef CONV_WINDOW

  // ---- epilogue: BN + SiLU, f32 store ----
#pragma unroll
  for (int ms = 0; ms < 4; ++ms) {
#pragma unroll
    for (int rr = 0; rr < 4; ++rr) {
      int o = o0 + ms * 16 + quad * 4 + rr;     // C/D: row = quad*4 + reg
      float inv = bng[o] * rsqrtf(bnv[o] + 1e-5f);
      float bias = bnb[o] - bnm[o] * inv;
      float* obp = out + ((size_t)(b * COUT + o)) * NPIX;
#pragma unroll
      for (int ns = 0; ns < 7; ++ns) {
        int pi = ns * 16 + ln;                  // C/D: col = lane&15
        int hr = (pi >= 56) ? 1 : 0;
        int wc = pi - hr * 56;
        int hg = h0 + 2 * wv + hr;
        float v = acc[ms][ns][rr] * inv + bias;
        v = v / (1.f + __expf(-v));             // SiLU
        obp[hg * 56 + wc] = v;
      }
    }
  }
}

extern "C" void kernel_launch(void* const* d_in, const int* in_sizes, int n_in,
                              void* d_out, int out_size, void* d_ws, size_t ws_size,
                              hipStream_t stream) {
  const float* x   = (const float*)d_in[0];
  const float* rw  = (const float*)d_in[1];
  const float* rb  = (const float*)d_in[2];
  const float* W   = (const float*)d_in[3];
  const float* bng = (const float*)d_in[4];
  const float* bnb = (const float*)d_in[5];
  const float* bnm = (const float*)d_in[6];
  const float* bnv = (const float*)d_in[7];
  float* out = (float*)d_out;

  char* wsb = (char*)d_ws;
  // cw: 16*16*256*168*2 = 22,020,096 B ; xq: 16*16*58*58*16*2 (+1 KiB pad) = 27,558,912 B
  // parts: 7*16*256*4 = 114,688 B   (total 49,693,696 B)
  u16*  cw    = (u16*)wsb;
  u16*  xq    = (u16*)(wsb + 22020096);
  float* parts = (float*)(wsb + 22020096 + 27558912);

  transpose_gap_kernel<<<dim3(7, 16, 16), 256, 0, stream>>>(x, xq, parts);
  combine_kernel<<<256, 256, 0, stream>>>(W, parts, rw, rb, cw);
  conv_kernel<<<dim3(256), 448, 0, stream>>>(xq, cw, bng, bnb, bnm, bnv, out);
}

// Round 7
// 225.715 us; speedup vs baseline: 1.0736x; 1.0057x over previous
//
#include <hip/hip_runtime.h>
#include <hip/hip_bf16.h>

typedef unsigned short u16;
typedef __attribute__((ext_vector_type(8))) short s16x8;
typedef __attribute__((ext_vector_type(4))) float f32x4;
typedef __attribute__((address_space(3))) u16 lds_u16;
typedef __attribute__((address_space(1))) const u16 g_u16;

#define CIN 256
#define COUT 256
#define NPIX 3136      // 56*56
#define CWROW 168      // 336B stride, gcd(336,128)=16 -> 2-way (free) on A-frag ds_read_b128
#define CWPB (16 * COUT * CWROW)   // 688128 elems per batch
// xq layout (CHANGED r7): [b][ck(16)][h'(58)][hf(2)][w'(58)][ci8(8)] bf16 — ci split into two
//   halves, each half contiguous over w'. B-frag lanes then read 16B at 16B stride (was 32B
//   stride = 4-way LDS bank conflict). Row still 928 elems; halo rows/cols zero.
// cw layout: [b][ck(16)][o(256)][t(10)+pad][ci(16)] bf16, t=9 zero pad, elems 160..167 dead pad.
// parts layout: [hg(7)][b(16)][c(256)] f32 raw GAP partial sums (no atomics, no memset).

__device__ __forceinline__ u16 f2b(float f) {   // f32 -> bf16 bits, RNE
  union { float f; unsigned u; } c; c.f = f;
  unsigned r = (c.u + 0x7FFFu + ((c.u >> 16) & 1u)) >> 16;
  return (u16)r;
}

// ---------------- K0: transpose x -> xq + fused GAP — r6 body, unit index remapped ----------------
__global__ __launch_bounds__(256)
void transpose_gap_kernel(const float* __restrict__ x, u16* __restrict__ xq,
                          float* __restrict__ parts) {
  const int hg = blockIdx.x, ck = blockIdx.y, b = blockIdx.z;
  const int tid = threadIdx.x;
  const int ci = tid >> 4, sub = tid & 15;
  __shared__ __align__(16) u16 tile[928 * 8];   // 14,848 B

  if (tid < 32) {                 // zero w'-halo units: (row, hf) x wp in {0,57}
    int r = tid >> 2, hf = (tid >> 1) & 1, wp = (tid & 1) * 57;
    int u = (r * 2 + hf) * 58 + wp;
    int us = u ^ ((u >> 3) & 7);
    *(uint4*)&tile[us * 8] = (uint4){0, 0, 0, 0};
  }
  const float* src = x + ((size_t)(b * CIN + ck * 16 + ci) * NPIX + (size_t)hg * 448);
  float s = 0.f;
#pragma unroll
  for (int it = 0; it < 7; ++it) {
    int p = it * 16 + sub;                      // [0,112): 8 rows x 14 float4
    int row = p / 14, wq = p - row * 14;
    float4 v = *(const float4*)(src + p * 4);
    s += v.x + v.y + v.z + v.w;
    u16 q[4] = { f2b(v.x), f2b(v.y), f2b(v.z), f2b(v.w) };
#pragma unroll
    for (int k = 0; k < 4; ++k) {
      int wp = wq * 4 + 1 + k;                  // w' in [1,56]
      int u = (row * 2 + (ci >> 3)) * 58 + wp;  // r7: half-major, w'-minor unit index
      int us = u ^ ((u >> 3) & 7);
      tile[us * 8 + (ci & 7)] = q[k];
    }
  }
  for (int off = 8; off; off >>= 1) s += __shfl_down(s, off, 16);  // 16 lanes share ci
  if (sub == 0) parts[(hg * 16 + b) * 256 + ck * 16 + ci] = s;     // plain store
  __syncthreads();
  uint4* dst = (uint4*)(xq + ((size_t)(b * 16 + ck) * 58 + hg * 8 + 1) * 928);
  for (int idx = tid; idx < 928; idx += 256) {  // 8 rows x 116 uint4, contiguous
    int us = idx ^ ((idx >> 3) & 7);
    dst[idx] = *(const uint4*)&tile[us * 8];
  }
  if (hg == 0 && tid < 116)                     // halo row h'=0
    ((uint4*)(xq + ((size_t)(b * 16 + ck) * 58) * 928))[tid] = (uint4){0, 0, 0, 0};
  if (hg == 6 && tid < 116)                     // halo row h'=57
    ((uint4*)(xq + ((size_t)(b * 16 + ck) * 58 + 57) * 928))[tid] = (uint4){0, 0, 0, 0};
}

// ---------------- K3: combine — r4/r6 VERBATIM (parts pre-reduce, LDS-staged stores) -------------
__global__ __launch_bounds__(256)
void combine_kernel(const float* __restrict__ W, const float* __restrict__ parts,
                    const float* __restrict__ rw, const float* __restrict__ rb,
                    u16* __restrict__ cw) {
  const int o = blockIdx.x, tid = threadIdx.x;
  __shared__ float pooled_lds[16 * 256];            // 16,384 B
  __shared__ float rs[128];
  __shared__ __align__(16) u16 st[2][16 * CWROW];   // 10,752 B
  for (int b = 0; b < 16; ++b) {                    // pre-reduce 7 hg-partials
    float s = 0.f;
#pragma unroll
    for (int hg = 0; hg < 7; ++hg) s += parts[(hg * 16 + b) * 256 + tid];
    pooled_lds[b * 256 + tid] = s;
  }
  for (int i = tid; i < (2 * 16 * CWROW) / 8; i += 256)   // zero staging (t=9 + pad)
    ((uint4*)st)[i] = (uint4){0, 0, 0, 0};
  __syncthreads();
  if (tid < 128) {                       // routing: r[b][e]
    int b = tid >> 3, e = tid & 7;
    float s = rb[e];
    const float* pb = pooled_lds + b * 256;
    const float* we = rw + e * CIN;
    for (int c = 0; c < CIN; ++c) s += (pb[c] * (1.f / 3136.f)) * we[c];
    rs[tid] = 1.f / (1.f + __expf(-s));
  }
  float wreg[8][9];
#pragma unroll
  for (int e = 0; e < 8; ++e) {
    const float* wp = W + ((size_t)(e * COUT + o)) * 2304 + tid;
#pragma unroll
    for (int k = 0; k < 9; ++k) wreg[e][k] = wp[k * 256];
  }
  int slot[9];
#pragma unroll
  for (int k = 0; k < 9; ++k) {
    int j = tid + k * 256, ci = j / 9, t = j - ci * 9;
    slot[k] = (ci >> 4) * CWROW + t * 16 + (ci & 15);
  }
  __syncthreads();
  for (int b = 0; b < 16; ++b) {
    u16* sb = st[b & 1];
    float rv[8];
#pragma unroll
    for (int e = 0; e < 8; ++e) rv[e] = rs[b * 8 + e];
#pragma unroll
    for (int k = 0; k < 9; ++k) {
      float a = 0.f;
#pragma unroll
      for (int e = 0; e < 8; ++e) a += rv[e] * wreg[e][k];
      sb[slot[k]] = f2b(a);
    }
    __syncthreads();
    u16* dstb = cw + (size_t)b * CWPB;
    for (int i = tid; i < 336; i += 256) {   // 16 ck x 21 uint4, each run 336B contiguous
      int ck = i / 21, q = i - ck * 21;
      *(uint4*)(dstb + ck * (256 * CWROW) + o * CWROW + q * 8) =
          *(const uint4*)(sb + ck * CWROW + q * 8);
    }
  }
}

// ---------------- K4: conv — r6 pipeline VERBATIM; B-frag addressing remapped to new xq ---------
// 448 threads (7 waves), grid 256 = 1 block/CU, 3 LDS buffers, counted vmcnt (depth-2).
// B-frag read now: lane ln reads 16B at addr (orow+dy)*928 + hf*464 + (wc+dx)*8 elems ->
// 16 lanes read 256B CONTIGUOUS (sequential banks, conflict-free; was 32B-stride 4-way).
__global__ __launch_bounds__(448, 1)
void conv_kernel(const u16* __restrict__ xq, const u16* __restrict__ cw,
                 const float* __restrict__ bng, const float* __restrict__ bnb,
                 const float* __restrict__ bnm, const float* __restrict__ bnv,
                 float* __restrict__ out) {
  const int l = blockIdx.x;
  const int xcd = l & 7, s = l >> 3;          // 32 blocks per XCD
  const int b = 2 * xcd + (s >> 4);
  const int rem = s & 15;
  const int ob = rem >> 2, hb = rem & 3;
  const int o0 = ob * 64, h0 = hb * 14;       // 4x14 = 56 rows, exact
  const int tid = threadIdx.x;
  const int wv = tid >> 6, lane = tid & 63, quad = lane >> 4, ln = lane & 15;

  __shared__ __align__(16) u16 xs[3][14848];  // 3 x 29,696 B (16 rows x 928, exact)
  __shared__ __align__(16) u16 as_[3][10752]; // 3 x 21,504 B -> total 153,600 B (1 blk/CU)

  f32x4 acc[4][7];
#pragma unroll
  for (int ms = 0; ms < 4; ++ms)
#pragma unroll
    for (int ns = 0; ns < 7; ++ns) acc[ms][ns] = (f32x4){0.f, 0.f, 0.f, 0.f};

  int bsite[7];
#pragma unroll
  for (int ns = 0; ns < 7; ++ns) {            // wave wv owns out-rows 2wv, 2wv+1 (of 14)
    int pi = ns * 16 + ln;
    int hr = (pi >= 56) ? 1 : 0;
    int wc = pi - hr * 56;
    bsite[ns] = (2 * wv + hr) * 928 + wc * 8; // r7: half-major row layout
  }
  int boffp[5];                               // ck-invariant tap offsets (hoisted)
#pragma unroll
  for (int tp = 0; tp < 5; ++tp) {
    int t = tp * 2 + (quad >> 1);
    int dy, dx;
    if (t < 9) { dy = t / 3; dx = t - dy * 3; } else { dy = 1; dx = 1; }  // t=9: zero weights
    boffp[tp] = dy * 928 + dx * 8 + (quad & 1) * 464;   // r7: dy row, dx pixel, hf half
  }
  int abase[4];
#pragma unroll
  for (int ms = 0; ms < 4; ++ms) abase[ms] = (ms * 16 + ln) * CWROW + quad * 8;

  // group map: xs = groups 0..28 (29 1KB-groups), as = groups 29..49 (21). wave0: 8, rest: 7.
  const int g0 = (wv == 0) ? 0 : 8 + (wv - 1) * 7;

  auto STAGE = [&](int ck, int buf) {
    const u16* xsrc = xq + ((size_t)(b * 16 + ck) * 58 + h0) * 928;      // 16 rows, exact
    const u16* asrc = cw + (size_t)b * CWPB + ((size_t)ck * COUT + o0) * CWROW; // 64 o contig
#pragma unroll
    for (int i = 0; i < 8; ++i) {
      if (i < 7 || wv == 0) {
        int G = g0 + i;
        if (G < 29)
          __builtin_amdgcn_global_load_lds((g_u16*)(xsrc + G * 512 + lane * 8),
                                           (lds_u16*)(&xs[buf][G * 512]), 16, 0, 0);
        else
          __builtin_amdgcn_global_load_lds((g_u16*)(asrc + (G - 29) * 512 + lane * 8),
                                           (lds_u16*)(&as_[buf][(G - 29) * 512]), 16, 0, 0);
      }
    }
  };

  auto COMPUTE = [&](int buf) {
#pragma unroll
    for (int tp = 0; tp < 5; ++tp) {
      s16x8 af[4];
#pragma unroll
      for (int ms = 0; ms < 4; ++ms)
        af[ms] = *(const s16x8*)&as_[buf][abase[ms] + tp * 32];
#pragma unroll
      for (int ns = 0; ns < 7; ++ns) {
        s16x8 bfr = *(const s16x8*)&xs[buf][bsite[ns] + boffp[tp]];
#pragma unroll
        for (int ms = 0; ms < 4; ++ms)
          acc[ms][ns] = __builtin_amdgcn_mfma_f32_16x16x32_bf16(af[ms], bfr, acc[ms][ns], 0, 0, 0);
      }
    }
  };

  STAGE(0, 0);
  STAGE(1, 1);
  // Window: counted drain (stage ck done, stage ck+1 still flying), barrier, issue ck+2, compute.
#define CONV_WINDOW(CK, BUF, SBUF, DO_STAGE, LAST)                                  \
  {                                                                                 \
    if (LAST)            asm volatile("s_waitcnt vmcnt(0)" ::: "memory");           \
    else if (wv == 0)    asm volatile("s_waitcnt vmcnt(8)" ::: "memory");           \
    else                 asm volatile("s_waitcnt vmcnt(7)" ::: "memory");           \
    __builtin_amdgcn_sched_barrier(0);                                              \
    __builtin_amdgcn_s_barrier();                                                   \
    __builtin_amdgcn_sched_barrier(0);                                              \
    if (DO_STAGE) STAGE((CK) + 2, SBUF);                                            \
    __builtin_amdgcn_s_setprio(1);                                                  \
    COMPUTE(BUF);                                                                   \
    __builtin_amdgcn_s_setprio(0);                                                  \
  }
  for (int jj = 0; jj < 5; ++jj) {            // windows ck=0..14 (buf indices static per slot)
    int ck = jj * 3;
    CONV_WINDOW(ck,     0, 2, true,      false);
    CONV_WINDOW(ck + 1, 1, 0, true,      false);
    CONV_WINDOW(ck + 2, 2, 1, (jj < 4),  false);
  }
  CONV_WINDOW(15, 0, 0, false, true);         // final window: full drain
#undef CONV_WINDOW

  // ---- epilogue: BN + SiLU, f32 store ----
#pragma unroll
  for (int ms = 0; ms < 4; ++ms) {
#pragma unroll
    for (int rr = 0; rr < 4; ++rr) {
      int o = o0 + ms * 16 + quad * 4 + rr;     // C/D: row = quad*4 + reg
      float inv = bng[o] * rsqrtf(bnv[o] + 1e-5f);
      float bias = bnb[o] - bnm[o] * inv;
      float* obp = out + ((size_t)(b * COUT + o)) * NPIX;
#pragma unroll
      for (int ns = 0; ns < 7; ++ns) {
        int pi = ns * 16 + ln;                  // C/D: col = lane&15
        int hr = (pi >= 56) ? 1 : 0;
        int wc = pi - hr * 56;
        int hg = h0 + 2 * wv + hr;
        float v = acc[ms][ns][rr] * inv + bias;
        v = v / (1.f + __expf(-v));             // SiLU
        obp[hg * 56 + wc] = v;
      }
    }
  }
}

extern "C" void kernel_launch(void* const* d_in, const int* in_sizes, int n_in,
                              void* d_out, int out_size, void* d_ws, size_t ws_size,
                              hipStream_t stream) {
  const float* x   = (const float*)d_in[0];
  const float* rw  = (const float*)d_in[1];
  const float* rb  = (const float*)d_in[2];
  const float* W   = (const float*)d_in[3];
  const float* bng = (const float*)d_in[4];
  const float* bnb = (const float*)d_in[5];
  const float* bnm = (const float*)d_in[6];
  const float* bnv = (const float*)d_in[7];
  float* out = (float*)d_out;

  char* wsb = (char*)d_ws;
  // cw: 16*16*256*168*2 = 22,020,096 B ; xq: 16*16*58*58*16*2 (+1 KiB pad) = 27,558,912 B
  // parts: 7*16*256*4 = 114,688 B   (total 49,693,696 B)
  u16*  cw    = (u16*)wsb;
  u16*  xq    = (u16*)(wsb + 22020096);
  float* parts = (float*)(wsb + 22020096 + 27558912);

  transpose_gap_kernel<<<dim3(7, 16, 16), 256, 0, stream>>>(x, xq, parts);
  combine_kernel<<<256, 256, 0, stream>>>(W, parts, rw, rb, cw);
  conv_kernel<<<dim3(256), 448, 0, stream>>>(xq, cw, bng, bnb, bnm, bnv, out);
}